// Round 4
// baseline (231.983 us; speedup 1.0000x reference)
//
#include <hip/hip_runtime.h>
#include <math.h>

// Match numpy's separate mul/add roundings — no implicit FMA contraction.
// (Explicit __builtin_fmaf below is intentional and unaffected.)
#pragma clang fp contract(off)

#define TPB 256
#define ROWLEN 1024

// Native clang vector type: required by __builtin_nontemporal_store
// (HIP's float4 is a class and is rejected by the builtin).
typedef float f32x4 __attribute__((ext_vector_type(4)));

// One WAVE per row of 1024 f32 (64 lanes x 16 elements), 4 rows per block.
// ALL per-element math is f32/int (full-rate VALU). f64 appears only in
// per-row constants (~15 ops, amortized 1/1024 per element) — rounds 1-2
// showed per-element f64 (quarter-rate-or-worse pipe) was the bottleneck.
//
// Numerics (vs the harness's numpy f32 reference):
//  - x/sf: double-float reciprocal (rh+rl) with exact-residual FMA =>
//    correctly-rounded f32 division except ~1e-15-relative corners
//    (~<1 element in 33.5M, +-1 ulp, cannot flip the row factor).
//  - q = floor(v/x0_int) via f32 recip-mul: validated rounds 1-2 (same
//    absmax), flips only at integer quotients where the polynomial is
//    continuous within 0.4% -> +-1 output quantum.
//  - exp_int: pure f32 mul/add/ldexp/floor, bit-identical to numpy.
//  - Row sum: per-lane u32 (exact), wave-reduced in u64, then f64 once.
//    Exact & order-independent => factor = floor(2^32/sum) matches the
//    reference (validated rounds 1-2) — the one catastrophic flip.
//  - Epilogue t1 = ei*factor bit-matches numpy's f32 mul; t2 = t1*invDen
//    is within 1 ulp of numpy's f32 division -> rare independent +-1
//    A-quantum flips (3.9e-4), threshold is 1.87e-3.
__global__ __launch_bounds__(TPB) void qsplit_int_softmax_kernel(
    const float* __restrict__ x,
    const float* __restrict__ scale_p,
    const float* __restrict__ thr_p,
    float* __restrict__ out)
{
    const int lane = threadIdx.x & 63;
    const int wid  = threadIdx.x >> 6;
    const int row  = blockIdx.x * 4 + wid;
    const size_t rbase = (size_t)row * ROWLEN + (size_t)lane * 4;

    const float sf  = scale_p[0];   // 0.05f
    const float thr = thr_p[0];     // 0.1f

    // ---- per-row constants (f64 fine: once per wave) ----
    const double sfd  = (double)sf;
    const double rd   = 1.0 / sfd;                 // 19.99999970197678
    const float  rh   = (float)rd;                 // 20.0f
    const float  rl   = (float)(rd - (double)rh);  // -1.25*2^-22 (exact)

    const double x0d    = floor(-0.69314718 / sfd);                  // -14
    const float  x0f    = (float)x0d;
    const float  bfc    = (float)floor((0.96963238 / 0.35815147) / sfd);   // 54
    const float  cfc    = (float)floor((1.0 / 0.35815147) / (sfd * sfd));  // 1116
    const float  clampf = (float)(15.0 * x0d);                       // -210
    const float  invx0f = (float)(1.0 / x0d);  // -0.071428575f

    // ---- load 16 elements (4x float4 = 1KB/instr per wave) ----
    f32x4 xv[4];
    #pragma unroll
    for (int k = 0; k < 4; ++k)
        xv[k] = *(const f32x4*)(x + rbase + (size_t)k * 256);

    // ---- x_int = x/sf via double-float reciprocal (all f32, ~CR division) --
    float xi[16];
    #pragma unroll
    for (int k = 0; k < 4; ++k) {
        #pragma unroll
        for (int jj = 0; jj < 4; ++jj) {
            const float xx = xv[k][jj];
            const float p  = xx * rh;
            const float e  = __builtin_fmaf(xx, rh, -p);   // exact residual
            xi[k*4+jj]     = p + __builtin_fmaf(xx, rl, e);
        }
    }

    // ---- wave max (f32) ----
    float m = xi[0];
    #pragma unroll
    for (int j = 1; j < 16; ++j) m = fmaxf(m, xi[j]);
    #pragma unroll
    for (int off = 1; off < 64; off <<= 1)
        m = fmaxf(m, __shfl_xor(m, off));

    // ---- integer exp per element (all f32/int, bit-matching numpy) ----
    float e16[16];
    unsigned int usum = 0;   // exact: 16 * 3.66e7 < 2^31
    #pragma unroll
    for (int j = 0; j < 16; ++j) {
        float v = xi[j] - m;                 // exact f32 sub
        v = fmaxf(v, clampf);                // >= -210
        const float qf = floorf(v * invx0f); // in [0,15]
        const int   qi = (int)qf;
        const float r  = v - x0f * qf;       // both steps exact in f32
        const float t  = r + bfc;
        const float z  = r * t + cfc;        // two roundings (contract off)
        float ei = floorf(ldexpf(z, 15 - qi)); // pow2 scale exact; floor exact
        ei = fmaxf(ei, 0.0f);
        e16[j] = ei;
        usum += (unsigned int)ei;            // exact integer accumulation
    }

    // ---- wave sum: u64 shuffle reduce (exact, order-independent) ----
    unsigned long long ws = usum;
    #pragma unroll
    for (int off = 1; off < 64; off <<= 1)
        ws += __shfl_xor(ws, off);
    const double s = (double)ws;             // < 3.8e10 < 2^53: exact

    // ---- row-uniform epilogue constants (f64 once per row) ----
    const double factor_d = floor(4294967296.0 / s);
    const float  fac_f = (float)factor_d;
    const float  ath_f = (float)((floor((double)thr * 256.0) * s) * (1.0 / 256.0));

    const float  osA  = thr / 255.0f;        // f32, as numpy
    const float  osB  = 1.0f / 255.0f;
    const float  invA = (float)(1.0 / (4294967296.0 * (double)osA));
    const float  invB = (float)(1.0 / (4294967296.0 * (double)osB));

    // ---- per-element quantize + nontemporal store ----
    #pragma unroll
    for (int k = 0; k < 4; ++k) {
        f32x4 o;
        #pragma unroll
        for (int jj = 0; jj < 4; ++jj) {
            const float ei  = e16[k*4+jj];
            const bool  isA = (ei <= ath_f);
            const float t1  = ei * fac_f;            // bit-matches numpy
            const float t2  = t1 * (isA ? invA : invB); // ~f32 division
            float si = floorf(t2);
            si = fminf(si, isA ? 3.0e38f : 255.0f);  // cap only on B path
            o[jj] = si * (isA ? osA : osB);
        }
        __builtin_nontemporal_store(o, (f32x4*)(out + rbase + (size_t)k * 256));
    }
}

extern "C" void kernel_launch(void* const* d_in, const int* in_sizes, int n_in,
                              void* d_out, int out_size, void* d_ws, size_t ws_size,
                              hipStream_t stream) {
    const float* x     = (const float*)d_in[0];
    const float* scale = (const float*)d_in[1];
    const float* thr   = (const float*)d_in[2];
    float* out = (float*)d_out;

    const int total = in_sizes[0];        // 2*16*1024*1024
    const int rows  = total / ROWLEN;     // 32768
    const int blocks = rows / 4;          // one wave per row

    qsplit_int_softmax_kernel<<<dim3(blocks), dim3(TPB), 0, stream>>>(
        x, scale, thr, out);
}